// Round 14
// baseline (240.105 us; speedup 1.0000x reference)
//
#include <hip/hip_runtime.h>
#include <stdint.h>

// DecayModel: out[b,i,h] = (fwd[i] + bwd[i]) / norm[i], decay = 0.5
//   fwd[i] = sum_{k<=i} 0.5^{i-k} x[k],  bwd[i] = sum_{k>=i} 0.5^{k-i} x[k]
//   norm[i] = 4 - 2^{-i} - 2^{-(S-1-i)}   (== 4.0f exactly for interior i)
//
// R19 -> R20: double pipeline depth AND slack.
// Falsified so far: load-sinking (R14), occupancy (R8/R16), read contiguity
// (R17), store policy (R19). R17 ledger re-audit: lookahead read buf m+2,
// so loads issued at iter m were required at iter m+1 -- ONE iteration of
// slack, and only 4KB/wave in flight -> ~8MB device-wide, marginal vs the
// 5.7-7.6MB latency-BW product: the system idles just below the knee.
// Fix, keeping everything else from the verified R17/R19 structure:
//   - W=8-row subtiles: K=8 lookahead reads ONE buffer ahead only
//   - loads issued at iter m needed at iter m+2 -> 2 iterations of slack
//   - ~8KB/wave in flight steady-state -> 64KB/CU, ~16MB device-wide
//   - barrier BEFORE prefetch (also fixes latent cross-wave overwrite race)
//   - always-prefetch (clamped; tail garbage never read) -> uniform ledger:
//       iter0 vmcnt(4), iter1 vmcnt(12), iters>=2 vmcnt(20)
//     (queue at iter m: [L_{m+1}:4, S_{m-2}:8, L_{m+2}:4, S_{m-1}:8]=24;
//      need L_{m+1} -> wait <=20; stores never force-drained)
// Half-row blocks (256 thr, v2f cols), C=128, NBUF=4 -> LDS 64KB, 2
// blocks/CU (de-synchronized pipelines). Plain stores (R19).
// Predict: dur 84 -> 50-65us if slack/in-flight was the limiter; if flat
// ~84us with in-flight 3x past the knee -> declare achievable roofline.

constexpr int B = 16;
constexpr int S = 2048;
constexpr int H2 = 512;          // float2 per full row (H=1024)
constexpr int BH = 256;          // float2 per block (half row)
constexpr int C = 128;           // rows per chunk
constexpr int W = 8;             // rows per subtile (== K taps)
constexpr int NT = C / W;        // 16 iterations
constexpr int THREADS = 256;     // 4 waves
constexpr int NCHUNK = S / C;    // 16
constexpr int NBLK = B * NCHUNK * 2;  // 512 blocks -> 2 per CU
constexpr int NXCD = 8;

typedef float v2f __attribute__((ext_vector_type(2)));

__device__ __forceinline__ void gload16(const v2f* g, v2f* l) {
    // HBM -> LDS direct, 16B/lane; LDS dest = wave-uniform base + lane*16.
    __builtin_amdgcn_global_load_lds(
        (const __attribute__((address_space(1))) uint32_t*)g,
        (__attribute__((address_space(3))) uint32_t*)l, 16, 0, 0);
}

// Stage one 8-row subtile: wave w DMAs rows {2w, 2w+1} (clamped), each row
// 2KB contiguous = 2 x 1KB instructions. 4 loads per wave per subtile.
__device__ __forceinline__ void stage(const v2f* __restrict__ xh, int row0,
                                      v2f (*buf)[BH], int w, int lane) {
#pragma unroll
    for (int k = 0; k < 2; ++k) {
        int g = row0 + 2 * w + k;
        g = g < 0 ? 0 : (g > S - 1 ? S - 1 : g);
        const v2f* src = xh + (size_t)g * H2 + 2 * lane;  // 16B per lane
        gload16(src, &buf[2 * w + k][0]);
        gload16(src + 128, &buf[2 * w + k][128]);
    }
}

template <int VM>
__device__ __forceinline__ void body(int m, int s0, bool edge,
                                     const v2f* __restrict__ xh,
                                     v2f* __restrict__ op, int tid, int w,
                                     int lane, v2f (*lds)[W][BH], v2f& facc) {
    // wait: drain loads for buf m+1 (and older); stores stay in flight
    if constexpr (VM == 4)
        asm volatile("s_waitcnt vmcnt(4)" ::: "memory");
    else if constexpr (VM == 12)
        asm volatile("s_waitcnt vmcnt(12)" ::: "memory");
    else
        asm volatile("s_waitcnt vmcnt(20)" ::: "memory");
    __builtin_amdgcn_s_barrier();  // all waves' DMA for bufs m,m+1 visible

    // prefetch subtile m+3 (always issued: uniform ledger; tail targets are
    // clamped rows whose contents are never read)
    stage(xh, s0 + (m + 3) * W, lds[(m + 3) & 3], w, lane);

    // ---- forward recurrence over subtile m (exact within chunk) ----
    const v2f fprev = facc;
    v2f f[W];
#pragma unroll
    for (int r = 0; r < W; ++r) {
        facc = 0.5f * facc + lds[m & 3][r][tid];
        f[r] = facc;
    }

    // ---- backward 8-tap lookahead from subtile m+1 only (K == W) ----
    v2f bacc = (v2f)0.0f;
    const int la0 = s0 + (m + 1) * W;
#pragma unroll
    for (int j = W - 1; j >= 0; --j) {
        v2f t = lds[(m + 1) & 3][j][tid];
        if (la0 + j >= S) t = (v2f)0.0f;  // rows past end contribute 0
        bacc = 0.5f * bacc + t;
    }

    // ---- backward march + combine + plain stores ----
#pragma unroll
    for (int r = W - 1; r >= 0; --r) {
        const v2f fr = f[r];
        const v2f fm_ = r ? f[r - 1] : fprev;
        bacc = 0.5f * bacc + (fr - 0.5f * fm_);  // recover x, extend bwd
        const int i = s0 + m * W + r;
        float rn = 0.25f;  // norm == 4.0f exactly for interior rows
        if (edge)
            rn = 1.0f / (4.0f - exp2f((float)(-i)) -
                         exp2f((float)(i - (S - 1))));
        op[(size_t)i * H2] = (fr + bacc) * rn;
    }
}

__global__ __launch_bounds__(THREADS, 2) void decay_kernel(
    const v2f* __restrict__ x, v2f* __restrict__ out) {
    __shared__ v2f lds[4][W][BH];  // 4 bufs x 8 rows x 2KB = 64 KiB

    // Bijective XCD swizzle (512 % 8 == 0): each XCD gets 64 consecutive
    // work items = 2 whole batches; chunk-neighbors share rows in L2.
    const int bid = blockIdx.x;
    const int swz = (bid & (NXCD - 1)) * (NBLK / NXCD) + (bid >> 3);
    const int h = swz & 1;
    const int cc = (swz >> 1) & (NCHUNK - 1);
    const int b = swz >> 5;
    const int s0 = cc * C;
    const bool edge = (cc == 0) | (cc == NCHUNK - 1);

    const int tid = threadIdx.x;
    const int w = tid >> 6;
    const int lane = tid & 63;
    const v2f* __restrict__ xh = x + (size_t)b * S * H2 + h * BH;
    v2f* __restrict__ op = out + (size_t)b * S * H2 + h * BH + tid;

    // ---- prologue: left halo -> buf3; subs 0,1,2 -> bufs 0,1,2 ----
    stage(xh, s0 - W, lds[3], w, lane);
    stage(xh, s0, lds[0], w, lane);
    stage(xh, s0 + W, lds[1], w, lane);
    stage(xh, s0 + 2 * W, lds[2], w, lane);
    asm volatile("s_waitcnt vmcnt(12)" ::: "memory");  // halo done
    __builtin_amdgcn_s_barrier();

    // fwd carry-in: 8-tap truncated scan over the halo (zero for chunk 0)
    v2f facc = (v2f)0.0f;
    if (cc > 0) {
#pragma unroll
        for (int r = 0; r < W; ++r) facc = 0.5f * facc + lds[3][r][tid];
    }
    // halo reads fully consumed before iter 0's prefetch overwrites buf3
    asm volatile("s_waitcnt lgkmcnt(0)" ::: "memory");
    __builtin_amdgcn_sched_barrier(0);
    __builtin_amdgcn_s_barrier();

    // ---- main loop: ledger-peeled prologue iters, then steady state ----
    body<4>(0, s0, edge, xh, op, tid, w, lane, lds, facc);
    body<12>(1, s0, edge, xh, op, tid, w, lane, lds, facc);
    for (int m = 2; m < NT; ++m)
        body<20>(m, s0, edge, xh, op, tid, w, lane, lds, facc);
}

extern "C" void kernel_launch(void* const* d_in, const int* in_sizes, int n_in,
                              void* d_out, int out_size, void* d_ws,
                              size_t ws_size, hipStream_t stream) {
    const v2f* x = (const v2f*)d_in[0];
    v2f* out = (v2f*)d_out;
    decay_kernel<<<dim3(NBLK), THREADS, 0, stream>>>(x, out);
}